// Round 6
// baseline (243.474 us; speedup 1.0000x reference)
//
#include <hip/hip_runtime.h>
#include <hip/hip_bf16.h>
#include <stdint.h>

// AtomicDifferentiatedDense: out[t,:] = relu(x[t,:] @ W[e(t)] + b[e(t)]), 0 if no match.
// T=262144 rows, K=N=128, E=4 experts (+1 inactive bucket).
//
// R4 (resubmit after infra timeout): LOCAL compaction, 2 launches.
//  k_prep : W (4x128x128 f32) -> bf16 MFMA B-fragment layout in ws (128KB, L2-hot).
//  k_fused: block = 256 consecutive rows. In-LDS 5-bucket compaction (no global
//           counters/perm, no inter-kernel dependency), then per-bucket 16-row
//           MFMA units; W-frags from L2; epilogue transposes via per-wave LDS
//           patch and stores full 128B-aligned segments. Bucket 4 = zero rows.
//  1024 blocks x 256 thr, ~34KB LDS, <=128 VGPR -> 4 blocks/CU, all resident.

typedef __attribute__((ext_vector_type(8))) short short8;
typedef __attribute__((ext_vector_type(4))) float f32x4;

#define PSTRIDE 132   // patch row stride in floats: 16B-aligned, 2-way-max banks

union U16 { uint4 u; short8 s; };

__device__ __forceinline__ uint32_t pkbf(float lo, float hi) {
    __hip_bfloat162 h = __float22bfloat162_rn(make_float2(lo, hi));
    uint32_t r; __builtin_memcpy(&r, &h, 4); return r;
}

// ---- k_prep: 32 blocks x 256 threads ----
__global__ __launch_bounds__(256) void k_prep(const float* __restrict__ W,
                                              uint32_t* __restrict__ ws) {
    const int T   = blockIdx.x * 256 + threadIdx.x;   // 8192 threads
    const int c16 = T & 15;
    const int g   = (T >> 4) & 3;
    const int nt  = (T >> 6) & 7;
    const int kk  = (T >> 9) & 3;
    const int e   = (T >> 11) & 3;
    float v[8];
    #pragma unroll
    for (int j = 0; j < 8; ++j)
        v[j] = W[(size_t)(e * 128 + kk * 32 + g * 8 + j) * 128 + nt * 16 + c16];
    uint4 pack = make_uint4(pkbf(v[0], v[1]), pkbf(v[2], v[3]),
                            pkbf(v[4], v[5]), pkbf(v[6], v[7]));
    *(uint4*)((char*)ws + 1024 + e * 32768 + ((kk * 8 + nt) * 64 + (g * 16 + c16)) * 16) = pack;
}

// ---- k_fused: 1024 blocks x 256 threads (4 waves), 256 rows/block ----
__global__ __launch_bounds__(256, 4) void k_fused(const float* __restrict__ x,
                                                  const int*   __restrict__ an,
                                                  const float* __restrict__ bvec,
                                                  const int*   __restrict__ cases,
                                                  const uint32_t* __restrict__ ws,
                                                  float* __restrict__ out) {
    __shared__ uint32_t cnt[5], curs[5], start[5];
    __shared__ uint8_t  units[24];
    __shared__ int      nunits_s;
    __shared__ uint16_t lridx[256];
    __shared__ float    patch[4][16 * PSTRIDE];   // 33792 B, per-wave regions

    const int tid  = threadIdx.x;
    const int lane = tid & 63, wv = tid >> 6;
    const int r0   = blockIdx.x << 8;

    if (tid < 5) cnt[tid] = 0;
    __syncthreads();

    const int c0 = cases[0], c1 = cases[1], c2 = cases[2], c3 = cases[3];
    const int a  = an[r0 + tid];
    const int bk = (a == c0) ? 0 : (a == c1) ? 1 : (a == c2) ? 2 : (a == c3) ? 3 : 4;
    atomicAdd(&cnt[bk], 1u);
    __syncthreads();

    if (tid == 0) {
        int n = 0; uint32_t run = 0;
        #pragma unroll
        for (int b = 0; b < 5; ++b) {
            start[b] = run; curs[b] = run;
            const int m = ((int)cnt[b] + 15) >> 4;
            for (int g = 0; g < m; ++g) units[n++] = (uint8_t)((b << 5) | g);
            run += cnt[b];
        }
        nunits_s = n;
    }
    __syncthreads();

    const uint32_t slot = atomicAdd(&curs[bk], 1u);
    lridx[slot] = (uint16_t)tid;
    __syncthreads();

    const int nunits = nunits_s;
    const int c16 = lane & 15, g4 = lane >> 4;
    const int sl8 = lane & 7,  r8 = lane >> 3;

    for (int ui = wv; ui < nunits; ui += 4) {
        const int ub   = units[ui] >> 5, ug = units[ui] & 31;
        const int sb   = (int)start[ub];
        const int nb   = (int)cnt[ub];

        if (ub == 4) {   // inactive rows -> zeros, full 128B segments
            const float4 z = make_float4(0.f, 0.f, 0.f, 0.f);
            #pragma unroll
            for (int h = 0; h < 2; ++h) {
                const int rr = r8 + h * 8;
                if (ug * 16 + rr < nb) {
                    float* op = out + (size_t)(r0 + lridx[sb + ug * 16 + rr]) * 128 + sl8 * 4;
                    #pragma unroll
                    for (int q = 0; q < 4; ++q) *(float4*)(op + q * 32) = z;
                }
            }
            continue;
        }

        const int rloc = ug * 16 + c16;
        const int arow = (rloc < nb) ? (r0 + (int)lridx[sb + rloc]) : -1;

        f32x4 acc[8];
        #pragma unroll
        for (int n = 0; n < 8; ++n) acc[n] = (f32x4){0.f, 0.f, 0.f, 0.f};

        const uint4* __restrict__ wf = (const uint4*)((const char*)ws + 1024 + ub * 32768);

        #pragma unroll
        for (int kk = 0; kk < 4; ++kk) {
            float4 fa = make_float4(0.f, 0.f, 0.f, 0.f);
            float4 fb = make_float4(0.f, 0.f, 0.f, 0.f);
            if (arow >= 0) {
                const float* p = x + (size_t)arow * 128 + kk * 32 + g4 * 8;
                fa = *(const float4*)p;
                fb = *(const float4*)(p + 4);
            }
            U16 av;
            av.u = make_uint4(pkbf(fa.x, fa.y), pkbf(fa.z, fa.w),
                              pkbf(fb.x, fb.y), pkbf(fb.z, fb.w));
            #pragma unroll
            for (int nt = 0; nt < 8; ++nt) {
                U16 wb; wb.u = wf[(kk * 8 + nt) * 64 + lane];
                acc[nt] = __builtin_amdgcn_mfma_f32_16x16x32_bf16(av.s, wb.s, acc[nt], 0, 0, 0);
            }
        }

        // bias+relu -> per-wave LDS patch (transpose); wave-internal, no barrier
        float* pt = &patch[wv][0];
        #pragma unroll
        for (int nt = 0; nt < 8; ++nt) {
            const float bb = bvec[ub * 128 + nt * 16 + c16];
            #pragma unroll
            for (int r = 0; r < 4; ++r)
                pt[(g4 * 4 + r) * PSTRIDE + nt * 16 + c16] = fmaxf(acc[nt][r] + bb, 0.f);
        }

        // full-line stores: per inst 8 rows x 128B-aligned segment
        #pragma unroll
        for (int h = 0; h < 2; ++h) {
            const int rr = r8 + h * 8;
            if (ug * 16 + rr < nb) {
                float* op = out + (size_t)(r0 + lridx[sb + ug * 16 + rr]) * 128 + sl8 * 4;
                #pragma unroll
                for (int q = 0; q < 4; ++q)
                    *(float4*)(op + q * 32) = *(const float4*)&pt[rr * PSTRIDE + q * 32 + sl8 * 4];
            }
        }
    }
}

extern "C" void kernel_launch(void* const* d_in, const int* in_sizes, int n_in,
                              void* d_out, int out_size, void* d_ws, size_t ws_size,
                              hipStream_t stream) {
    const float* x     = (const float*)d_in[0];
    const int*   an    = (const int*)d_in[1];
    const float* W     = (const float*)d_in[2];
    const float* bvec  = (const float*)d_in[3];
    const int*   cases = (const int*)d_in[4];
    float*    out = (float*)d_out;
    uint32_t* ws  = (uint32_t*)d_ws;

    k_prep <<<32,   256, 0, stream>>>(W, ws);
    k_fused<<<1024, 256, 0, stream>>>(x, an, bvec, cases, ws, out);
}